// Round 7
// baseline (104.408 us; speedup 1.0000x reference)
//
#include <hip/hip_runtime.h>
#include <math.h>

#define DD 128
#define BB 8192
#define NN 64
#define LOGC 235.24826450039622f   // 128 * log(2*pi)
#define CLAMP_M 1.0e12f            // clamp on solve outputs: keeps all downstream f32 finite (no NaN)
#define YCLAMP 1.0e18f             // fallback-path clamp
#define KP 136                     // xs LDS pitch in bf16 (128+8)
#define PITCH 129                  // kernel-A LDS pitch in f32 (stride mod 32 = 1)

typedef __attribute__((ext_vector_type(8))) short bf16x8;   // 8 bf16 = 4 VGPRs
typedef __attribute__((ext_vector_type(4))) float f32x4;

__device__ __forceinline__ unsigned int f2bf(float x) {
    unsigned int u = __float_as_uint(x);
    return (u + 0x7FFFu + ((u >> 16) & 1u)) >> 16;
}
__device__ __forceinline__ unsigned int pack2(float lo, float hi) {
    return f2bf(lo) | (f2bf(hi) << 16);
}
__device__ __forceinline__ float clampM(float x) {
    return fminf(fmaxf(x, -CLAMP_M), CLAMP_M);
}
__device__ __forceinline__ float lane_bcast(float v, int j) {
    return __int_as_float(__builtin_amdgcn_readlane(__float_as_int(v), j));
}
// async 16B global->LDS (guide §5: width 16 verified on gfx950, m97)
__device__ __forceinline__ void gl_lds16(const unsigned short* g, unsigned short* l) {
    __builtin_amdgcn_global_load_lds(
        (const __attribute__((address_space(1))) void*)g,
        (__attribute__((address_space(3))) void*)l, 16, 0, 0);
}

// ---------------------------------------------------------------------------
// Kernel A (R7): 8 column-chains per wave -> issue-bound, not latency-bound.
// R6 post-mortem: with 4 chains the serial j-loop still paid LDS latency in
// the dependency chain at 2 waves/SIMD of cover; 8 chains amortize the 3 LDS
// reads per step over ~48 VALU ops. No ybuf: lane l holds row l (and l+64)
// of all 8 chains in registers, so M rows store directly as 16B uint4.
// Grid (5, 64): grp 0..3 own columns grp*32 + w*8 .. +7; grp 4: wave0 solves
// RHS=mu -> vout, wave1 -> logdet/termout.
// ---------------------------------------------------------------------------
__global__ __launch_bounds__(256, 2)
void solve_columns(const float* __restrict__ chol,
                   const float* __restrict__ means,
                   unsigned short* __restrict__ Mout,  // (N,D,D) bf16 row-major
                   float* __restrict__ vout,           // (N,D)
                   float* __restrict__ termout)        // (N)
{
    const int n = blockIdx.y;
    const int grp = blockIdx.x;      // 0..4
    const int t = threadIdx.x;
    const int lane = t & 63;
    const int w = t >> 6;
    const float* __restrict__ Ln = chol + (size_t)n * DD * DD;

    const bool is_mu = (grp == 4);
    const int jmin = is_mu ? 0 : grp * 32;   // LsT rows below this never read

    __shared__ float LsT[DD][PITCH];   // [j][i] = (i>j) ? L[i][j] : 0
    __shared__ float s_invd[DD];
    __shared__ float s_raw[DD];

    // --- stage L transposed + tril-masked; skip rows j < jmin ---
    #pragma unroll
    for (int it = 0; it < 16; ++it) {
        const int id = it * 256 + t;        // 4096 float4 chunks
        const int i = id >> 5;              // row of L
        const int j0 = (id & 31) * 4;       // col of L
        if (j0 < jmin) continue;
        if (i <= j0) {
            LsT[j0 + 0][i] = 0.0f;
            LsT[j0 + 1][i] = 0.0f;
            LsT[j0 + 2][i] = 0.0f;
            LsT[j0 + 3][i] = 0.0f;
        } else {
            const float4 vv = *(const float4*)(Ln + (size_t)i * DD + j0);
            LsT[j0 + 0][i] = (i > j0 + 0) ? vv.x : 0.0f;
            LsT[j0 + 1][i] = (i > j0 + 1) ? vv.y : 0.0f;
            LsT[j0 + 2][i] = (i > j0 + 2) ? vv.z : 0.0f;
            LsT[j0 + 3][i] = (i > j0 + 3) ? vv.w : 0.0f;
        }
    }
    if (t < DD) {
        const float raw = Ln[(size_t)t * DD + t];
        s_raw[t] = raw;
        s_invd[t] = __expf(-raw);           // 1/exp(raw): diag of L is exp(raw)
    }
    __syncthreads();

    if (is_mu) {
        if (w == 0) {
            float rl = means[(size_t)n * DD + lane];
            float rh = means[(size_t)n * DD + 64 + lane];
            #pragma unroll 4
            for (int j = 0; j < 64; ++j) {
                const float y = clampM(lane_bcast(rl, j) * s_invd[j]);
                rl = fmaf(-LsT[j][lane], y, rl);
                rh = fmaf(-LsT[j][64 + lane], y, rh);
            }
            #pragma unroll 4
            for (int j = 64; j < 128; ++j) {
                const float y = clampM(lane_bcast(rh, j - 64) * s_invd[j]);
                rh = fmaf(-LsT[j][64 + lane], y, rh);
            }
            vout[(size_t)n * DD + lane] = clampM(rl * s_invd[lane]);
            vout[(size_t)n * DD + 64 + lane] = clampM(rh * s_invd[64 + lane]);
        } else if (w == 1) {
            float v = s_raw[lane] + s_raw[64 + lane];
            #pragma unroll
            for (int o = 32; o > 0; o >>= 1) v += __shfl_down(v, o);
            if (lane == 0) termout[n] = LOGC + 2.0f * v;
        }
        return;
    }

    // --- 8 interleaved column chains: columns c0..c0+7 ---
    const int c0 = grp * 32 + w * 8;
    float rl[8], rh[8];
    #pragma unroll
    for (int ch = 0; ch < 8; ++ch) {
        rl[ch] = (lane == c0 + ch) ? 1.0f : 0.0f;
        rh[ch] = (lane + 64 == c0 + ch) ? 1.0f : 0.0f;
    }

    // steps j in [c0, 64): both halves update (chains with c>j have y=0 -> no-op)
    #pragma unroll 2
    for (int j = c0; j < 64; ++j) {
        const float invd = s_invd[j];
        const float Ll = LsT[j][lane];
        const float Lh = LsT[j][64 + lane];
        float yv[8];
        #pragma unroll
        for (int ch = 0; ch < 8; ++ch)
            yv[ch] = clampM(lane_bcast(rl[ch], j) * invd);
        #pragma unroll
        for (int ch = 0; ch < 8; ++ch) {
            rl[ch] = fmaf(-Ll, yv[ch], rl[ch]);
            rh[ch] = fmaf(-Lh, yv[ch], rh[ch]);
        }
    }
    // steps j in [max(c0,64), 128): rows 0..63 frozen, only hi half updates
    #pragma unroll 2
    for (int j = (c0 > 64 ? c0 : 64); j < 128; ++j) {
        const float invd = s_invd[j];
        const float Lh = LsT[j][64 + lane];
        float yv[8];
        #pragma unroll
        for (int ch = 0; ch < 8; ++ch)
            yv[ch] = clampM(lane_bcast(rh[ch], j - 64) * invd);
        #pragma unroll
        for (int ch = 0; ch < 8; ++ch)
            rh[ch] = fmaf(-Lh, yv[ch], rh[ch]);
    }

    // frozen-residual: y_l = clamp(r_l * invd[l]); lane l holds row l (and
    // l+64) of all 8 chains -> pack and store two 16B row-chunks directly.
    const float i_lo = s_invd[lane], i_hi = s_invd[64 + lane];
    float ylo[8], yhi[8];
    #pragma unroll
    for (int ch = 0; ch < 8; ++ch) {
        ylo[ch] = clampM(rl[ch] * i_lo);
        yhi[ch] = clampM(rh[ch] * i_hi);
    }
    uint4 plo, phi;
    plo.x = pack2(ylo[0], ylo[1]); plo.y = pack2(ylo[2], ylo[3]);
    plo.z = pack2(ylo[4], ylo[5]); plo.w = pack2(ylo[6], ylo[7]);
    phi.x = pack2(yhi[0], yhi[1]); phi.y = pack2(yhi[2], yhi[3]);
    phi.z = pack2(yhi[4], yhi[5]); phi.w = pack2(yhi[6], yhi[7]);
    *(uint4*)&Mout[((size_t)n * DD + lane) * DD + c0] = plo;
    *(uint4*)&Mout[((size_t)n * DD + 64 + lane) * DD + c0] = phi;
}

// ---------------------------------------------------------------------------
// Kernel B (unchanged from R6): quad[b,n] = ||M_n x_b - v_n||^2, bf16 MFMA.
// Async global_load_lds double-buffered staging, one barrier per n-iteration.
// ---------------------------------------------------------------------------
__global__ __launch_bounds__(256, 2)
void emission_mfma(const float* __restrict__ x,
                   const unsigned short* __restrict__ Mws,
                   const float* __restrict__ vws,
                   const float* __restrict__ termws,
                   float* __restrict__ out)
{
    const int btile = blockIdx.x;            // 64 tiles of 128 b
    const int ngrp = blockIdx.y;             // 8 groups of 8 n
    const int t = threadIdx.x;
    const int lane = t & 63;
    const int w = t >> 6;
    const int wi = w >> 1;                   // i-half
    const int wb = w & 1;                    // b-half

    // LDS arena: xs/P1 overlay | P0 | sv8 | qbuf | redbuf[2] | sterm
    __shared__ __align__(16) char smem[34816 + 32768 + 4096 + 4096 + 2048 + 32];
    unsigned short* xs = (unsigned short*)smem;              // 128*KP bf16
    unsigned short* P1 = (unsigned short*)smem;              // overlays xs
    unsigned short* P0 = (unsigned short*)(smem + 34816);
    float* sv8   = (float*)(smem + 34816 + 32768);           // [8][128]
    float* qbuf  = (float*)(smem + 34816 + 32768 + 4096);    // [8][128]
    float* redbuf = (float*)(smem + 34816 + 32768 + 8192);   // [2][256]
    float* sterm = (float*)(smem + 34816 + 32768 + 8192 + 2048); // [8]

    const int bbase = btile * 128;
    const unsigned short* __restrict__ Mbase = Mws + (size_t)(ngrp * 8) * DD * DD;

    auto stage_M = [&](const unsigned short* Mn, unsigned short* Pbuf) {
        #pragma unroll
        for (int k = 0; k < 8; ++k) {
            const int s = w * 512 + k * 64 + lane;
            const int row = s >> 4;
            const int kc = (s & 15) ^ (row & 15);
            gl_lds16(Mn + (size_t)row * DD + kc * 8,
                     Pbuf + (size_t)(w * 512 + k * 64) * 8);
        }
    };

    // --- prologue: stage x (f32->bf16), sv8, sterm; issue M0 -> P0 ---
    #pragma unroll
    for (int it = 0; it < 8; ++it) {
        const int id = it * 256 + t;
        const int brow = id >> 4;
        const int koff = (id & 15) * 8;
        const float4* px = (const float4*)(x + (size_t)(bbase + brow) * DD + koff);
        const float4 a = px[0], b = px[1];
        uint4 p;
        p.x = pack2(a.x, a.y);
        p.y = pack2(a.z, a.w);
        p.z = pack2(b.x, b.y);
        p.w = pack2(b.z, b.w);
        *(uint4*)&xs[brow * KP + koff] = p;
    }
    *(float4*)&sv8[4 * t] = *(const float4*)&vws[(size_t)ngrp * 8 * DD + 4 * t];
    if (t < 8) sterm[t] = termws[ngrp * 8 + t];
    stage_M(Mbase, P0);
    __syncthreads();   // xs + sv8 visible (M0 drained here too)

    // --- preload B-operand frags (x) to registers ---
    bf16x8 bf[4][4];
    #pragma unroll
    for (int bt = 0; bt < 4; ++bt)
        #pragma unroll
        for (int ks = 0; ks < 4; ++ks) {
            const int col = wb * 64 + bt * 16 + (lane & 15);
            const int k = ks * 32 + (lane >> 4) * 8;
            bf[bt][ks] = *(const bf16x8*)&xs[col * KP + k];
        }
    __syncthreads();   // all frags read; xs region free for P1

    const f32x4 zero = {0.0f, 0.0f, 0.0f, 0.0f};

    for (int nl = 0; nl < 8; ++nl) {
        if (nl < 7)
            stage_M(Mbase + (size_t)(nl + 1) * DD * DD, ((nl + 1) & 1) ? P1 : P0);
        if (nl > 0 && t < 128) {
            float* rb = redbuf + ((nl - 1) & 1) * 256;
            qbuf[(nl - 1) * 128 + t] = rb[t] + rb[128 + t];
        }

        const unsigned short* Pc = (nl & 1) ? P1 : P0;

        f32x4 acc[4][4];
        #pragma unroll
        for (int it = 0; it < 4; ++it)
            #pragma unroll
            for (int bt = 0; bt < 4; ++bt) acc[it][bt] = zero;

        #pragma unroll
        for (int ks = 0; ks < 4; ++ks) {
            bf16x8 af[4];
            #pragma unroll
            for (int it = 0; it < 4; ++it) {
                const int row = wi * 64 + it * 16 + (lane & 15);
                const int kchunk = ks * 4 + (lane >> 4);
                af[it] = *(const bf16x8*)((const char*)Pc + row * 256 +
                                          ((kchunk ^ (row & 15)) * 16));
            }
            #pragma unroll
            for (int it = 0; it < 4; ++it)
                #pragma unroll
                for (int bt = 0; bt < 4; ++bt)
                    acc[it][bt] = __builtin_amdgcn_mfma_f32_16x16x32_bf16(
                        af[it], bf[bt][ks], acc[it][bt], 0, 0, 0);
        }

        float p[4] = {0.0f, 0.0f, 0.0f, 0.0f};
        #pragma unroll
        for (int it = 0; it < 4; ++it) {
            const int rowbase = wi * 64 + it * 16 + (lane >> 4) * 4;  // C row = q*4+reg
            const f32x4 v4 = *(const f32x4*)&sv8[nl * 128 + rowbase];
            #pragma unroll
            for (int bt = 0; bt < 4; ++bt) {
                const f32x4 a = acc[it][bt];
                const float t0 = a.x - v4.x, t1 = a.y - v4.y;
                const float t2 = a.z - v4.z, t3 = a.w - v4.w;
                p[bt] += t0 * t0 + t1 * t1 + t2 * t2 + t3 * t3;
            }
        }
        float* rb = redbuf + (nl & 1) * 256;
        #pragma unroll
        for (int bt = 0; bt < 4; ++bt) {
            float pv = p[bt];
            pv += __shfl_xor(pv, 16);
            pv += __shfl_xor(pv, 32);
            if (lane < 16) rb[wi * 128 + wb * 64 + bt * 16 + lane] = pv;
        }
        __syncthreads();   // drains next-M loads (covered by compute); redbuf ready
    }

    if (t < 128) {
        qbuf[7 * 128 + t] = redbuf[256 + t] + redbuf[256 + 128 + t];  // nl=7 parity 1
        float o[8];
        #pragma unroll
        for (int j = 0; j < 8; ++j)
            o[j] = -0.5f * (sterm[j] + qbuf[j * 128 + t]);
        float* po = &out[(size_t)(bbase + t) * NN + ngrp * 8];
        *(float4*)&po[0] = make_float4(o[0], o[1], o[2], o[3]);
        *(float4*)&po[4] = make_float4(o[4], o[5], o[6], o[7]);
    }
}

// ---------------------------------------------------------------------------
// Fallback if workspace is too small: direct per-(b,n) solve (R2 path).
// ---------------------------------------------------------------------------
__global__ __launch_bounds__(256, 2)
void emission_solve_fb(const float* __restrict__ xin,
                       const float* __restrict__ means,
                       const float* __restrict__ chol,
                       float* __restrict__ out)
{
    const int n = blockIdx.y;
    const int t = threadIdx.x;
    const int b = blockIdx.x * 256 + t;
    const float* __restrict__ Ln = chol + (size_t)n * DD * DD;

    __shared__ float s_invd[DD];
    __shared__ float s_mu[DD];
    __shared__ float s_part[4];

    float raw = 0.0f;
    if (t < DD) {
        raw = Ln[t * DD + t];
        s_invd[t] = 1.0f / expf(raw);
        s_mu[t] = means[n * DD + t];
    }
    float v = raw;
    #pragma unroll
    for (int o = 32; o > 0; o >>= 1) v += __shfl_down(v, o);
    if ((t & 63) == 0) s_part[t >> 6] = v;
    __syncthreads();

    const float term = LOGC + 2.0f * (s_part[0] + s_part[1] + s_part[2] + s_part[3]);

    float y[DD];
    float quad = 0.0f;
    #pragma unroll
    for (int i = 0; i < DD; ++i) {
        const float xv = xin[(size_t)b * DD + i] - s_mu[i];
        float sA = 0.0f, sB = 0.0f;
        #pragma unroll
        for (int j = 0; j + 1 < i; j += 2) {
            sA = fmaf(Ln[i * DD + j], y[j], sA);
            sB = fmaf(Ln[i * DD + j + 1], y[j + 1], sB);
        }
        if (i & 1) sA = fmaf(Ln[i * DD + (i - 1)], y[i - 1], sA);
        const float s = xv - sA - sB;
        float yi = s * s_invd[i];
        yi = fminf(fmaxf(yi, -YCLAMP), YCLAMP);
        y[i] = yi;
        quad = fmaf(yi, yi, quad);
    }
    out[(size_t)b * NN + n] = -0.5f * (term + quad);
}

extern "C" void kernel_launch(void* const* d_in, const int* in_sizes, int n_in,
                              void* d_out, int out_size, void* d_ws, size_t ws_size,
                              hipStream_t stream) {
    const float* x     = (const float*)d_in[0];  // (8192,128)
    const float* means = (const float*)d_in[1];  // (64,128)
    const float* chol  = (const float*)d_in[2];  // (64,128,128)
    float* out = (float*)d_out;                  // (8192,64)

    const size_t needM = (size_t)NN * DD * DD * sizeof(unsigned short); // 2 MiB
    const size_t needV = (size_t)NN * DD * sizeof(float);               // 32 KiB
    const size_t needT = (size_t)NN * sizeof(float);

    if (ws_size >= needM + needV + needT) {
        unsigned short* Mws = (unsigned short*)d_ws;
        float* vws = (float*)((char*)d_ws + needM);
        float* tws = (float*)((char*)d_ws + needM + needV);
        solve_columns<<<dim3(5, NN), 256, 0, stream>>>(chol, means, Mws, vws, tws);
        emission_mfma<<<dim3(BB / 128, 8), 256, 0, stream>>>(x, Mws, vws, tws, out);
    } else {
        emission_solve_fb<<<dim3(BB / 256, NN), 256, 0, stream>>>(x, means, chol, out);
    }
}